// Round 4
// baseline (68308.929 us; speedup 1.0000x reference)
//
#include <hip/hip_runtime.h>

#define SEQ  8192
#define HID  1024
#define NBLK 64
#define WPB  16            // waves per block
#define TPB  (WPB * 64)    // 1024 threads
#define KCH  (HID / 64)    // 16 K-chunks per dot product

// slots: 2 parity slots x HID u64 words, each word = (step_tag<<32)|f32bits(h[j])
#define SLOT_WORDS (2 * HID)

__device__ __forceinline__ float sigmoidf_fast(float a) {
    return 1.0f / (1.0f + __expf(-a));
}
__device__ __forceinline__ float tanhf_fast(float a) {
    float t = fabsf(a);
    float e = __expf(-2.0f * t);
    float r = (1.0f - e) / (1.0f + e);
    return copysignf(r, a);
}

__global__ __launch_bounds__(TPB, 4) void gru_persistent(
    const float* __restrict__ inp,   // [SEQ, HID]
    const float* __restrict__ Wih,   // [3*HID, HID]
    const float* __restrict__ Whh,   // [3*HID, HID]
    const float* __restrict__ bih,   // [3*HID]
    const float* __restrict__ bhh,   // [3*HID]
    float* __restrict__ out,         // [SEQ, HID]
    unsigned long long* __restrict__ slots)  // [2][HID]
{
    __shared__ float hbuf[2][HID];   // double-buffered h vector (8 KB)
    const int tid  = threadIdx.x;
    const int wave = tid >> 6;
    const int lane = tid & 63;
    const int j    = blockIdx.x * WPB + wave;  // this wave's output row, 0..1023
    const int sl   = (wave << 6) | lane;       // this wave's slot-slice word index

    // ---- persistent W_hh rows (j, HID+j, 2*HID+j) in VGPRs: 48 regs/thread ----
    float wr[KCH], wz[KCH], wn[KCH];
    {
        const float* Wr = Whh + (size_t)j * HID;
        const float* Wz = Whh + (size_t)(HID + j) * HID;
        const float* Wn = Whh + (size_t)(2 * HID + j) * HID;
#pragma unroll
        for (int k = 0; k < KCH; ++k) {
            wr[k] = Wr[lane + 64 * k];
            wz[k] = Wz[lane + 64 * k];
            wn[k] = Wn[lane + 64 * k];
        }
    }
    // biases added ONCE, after the 64-lane reduction
    const float bxr = bih[j], bxz = bih[HID + j], bxn = bih[2 * HID + j];
    const float bhr = bhh[j], bhz = bhh[HID + j], bhn = bhh[2 * HID + j];
    const float* Ur = Wih + (size_t)j * HID;
    const float* Uz = Wih + (size_t)(HID + j) * HID;
    const float* Un = Wih + (size_t)(2 * HID + j) * HID;

    // ---- h_0 = 0 in LDS buffer 0 ----
    hbuf[0][tid] = 0.0f;             // TPB == HID
    __syncthreads();

    // ---- x-side projection for t=1 (pipelined one step ahead) ----
    float xr = 0.0f, xz = 0.0f, xn = 0.0f;
    {
        const float* x = inp;        // row 0
#pragma unroll
        for (int k = 0; k < KCH; ++k) {
            float xv = x[lane + 64 * k];
            xr = fmaf(Ur[lane + 64 * k], xv, xr);
            xz = fmaf(Uz[lane + 64 * k], xv, xz);
            xn = fmaf(Un[lane + 64 * k], xv, xn);
        }
#pragma unroll
        for (int m = 32; m >= 1; m >>= 1) {
            xr += __shfl_xor(xr, m, 64);
            xz += __shfl_xor(xz, m, 64);
            xn += __shfl_xor(xn, m, 64);
        }
        xr += bxr; xz += bxz; xn += bxn;
    }

    for (int t = 1; t <= SEQ; ++t) {
        // ---- h-side matvec: h_{t-1} from hbuf[(t-1)&1], weights from VGPRs ----
        const float* hb = hbuf[(t - 1) & 1];
        float hr = 0.0f, hz = 0.0f, hn = 0.0f;
#pragma unroll
        for (int k = 0; k < KCH; ++k) {
            float hv = hb[lane + 64 * k];
            hr = fmaf(wr[k], hv, hr);
            hz = fmaf(wz[k], hv, hz);
            hn = fmaf(wn[k], hv, hn);
        }
#pragma unroll
        for (int m = 32; m >= 1; m >>= 1) {
            hr += __shfl_xor(hr, m, 64);
            hz += __shfl_xor(hz, m, 64);
            hn += __shfl_xor(hn, m, 64);
        }
        hr += bhr; hz += bhz; hn += bhn;

        const float hprev = hb[j];
        const float r = sigmoidf_fast(xr + hr);
        const float z = sigmoidf_fast(xz + hz);
        const float n = tanhf_fast(xn + r * hn);
        const float hnew = (1.0f - z) * n + z * hprev;

        if (lane == 0) {
            // publish FIRST — the only thing other blocks' critical paths wait on
            unsigned long long pub = ((unsigned long long)(unsigned)t << 32)
                                   | (unsigned long long)__float_as_uint(hnew);
            __hip_atomic_store(slots + (t & 1) * HID + j, pub,
                               __ATOMIC_RELAXED, __HIP_MEMORY_SCOPE_AGENT);
            __builtin_nontemporal_store(hnew, out + (size_t)(t - 1) * HID + j);
        }

        if (t < SEQ) {
            // ---- x-side projection for t+1: hides in the publish->visibility gap ----
            {
                const float* x = inp + (size_t)t * HID;
                xr = 0.0f; xz = 0.0f; xn = 0.0f;
#pragma unroll
                for (int k = 0; k < KCH; ++k) {
                    float xv = x[lane + 64 * k];
                    xr = fmaf(Ur[lane + 64 * k], xv, xr);
                    xz = fmaf(Uz[lane + 64 * k], xv, xz);
                    xn = fmaf(Un[lane + 64 * k], xv, xn);
                }
#pragma unroll
                for (int m = 32; m >= 1; m >>= 1) {
                    xr += __shfl_xor(xr, m, 64);
                    xz += __shfl_xor(xz, m, 64);
                    xn += __shfl_xor(xn, m, 64);
                }
                xr += bxr; xz += bxz; xn += bxn;
            }

            // ---- slice-parallel poll: each wave owns 64 words; one 512B load/iter.
            //      Values ride with tags (self-verifying), write straight to LDS slice.
            //      Safe vs. siblings: writes go to the OTHER parity buffer than the
            //      one being read this step; a wave only writes after its poll passes.
            const unsigned long long* rd = slots + (t & 1) * HID;
            const unsigned expect = (unsigned)t;
            for (;;) {
                unsigned long long wv = __hip_atomic_load(
                    rd + sl, __ATOMIC_RELAXED, __HIP_MEMORY_SCOPE_AGENT);
                if (__all((unsigned)(wv >> 32) == expect)) {
                    hbuf[t & 1][sl] = __uint_as_float((unsigned)(wv & 0xffffffffu));
                    break;
                }
                __builtin_amdgcn_s_sleep(1);
            }
        }
        __syncthreads();   // slice writes visible to all waves before next compute
    }
}

extern "C" void kernel_launch(void* const* d_in, const int* in_sizes, int n_in,
                              void* d_out, int out_size, void* d_ws, size_t ws_size,
                              hipStream_t stream) {
    const float* inp = (const float*)d_in[0];
    const float* Wih = (const float*)d_in[1];
    const float* Whh = (const float*)d_in[2];
    const float* bih = (const float*)d_in[3];
    const float* bhh = (const float*)d_in[4];
    float* out = (float*)d_out;
    unsigned long long* slots = (unsigned long long*)d_ws;

    // zero both parity slots (tags monotone from 1, so zeros/poison never false-match;
    // memset kept for hygiene — it is graph-captured and replays every launch)
    hipMemsetAsync(slots, 0, SLOT_WORDS * sizeof(unsigned long long), stream);

    gru_persistent<<<dim3(NBLK), dim3(TPB), 0, stream>>>(
        inp, Wih, Whh, bih, bhh, out, slots);
}